// Round 5
// baseline (173.547 us; speedup 1.0000x reference)
//
#include <hip/hip_runtime.h>
#include <cfloat>
#include <stdint.h>

#define B_   16
#define N_   2048
#define KK   10          // window = K+1
#define H_   128
#define SUB  32          // chunk size
#define NCH  (N_ / SUB)  // 64 chunks

#define RANK_BLOCKS (B_ * 32)                  // 512: 64-elem segments, 256 thr
#define WEFF_OUT    (H_ * KK * 2 + H_)         // 2688 outputs
#define WEFF_BLOCKS ((WEFF_OUT * 4) / 256)     // 42 (4 lanes/output, exact)
#define NITEMS      (B_ * NCH)                 // 1024 half-tile work items

__device__ inline uint32_t f32_ordered(float f) {
    uint32_t u = __float_as_uint(f);
    return (u & 0x80000000u) ? ~u : (u | 0x80000000u);
}

// ---- setup (R3 structure, ~6us) + work-queue counter reset.
__global__ __launch_bounds__(256) void setup_kernel(
    const float* __restrict__ x,
    const float* __restrict__ Wconv, const float* __restrict__ bconv,
    const float* __restrict__ b1,    const float* __restrict__ W2,
    const float* __restrict__ b2,
    float4* __restrict__ xsorted,    // [B][N] (px,py,sm,orig_idx_bits)
    float*  __restrict__ weff,       // [H*20]
    float*  __restrict__ btot,       // [H]
    int*    __restrict__ gcnt)       // work-queue counter (reset here)
{
#pragma clang fp contract(off)
    __shared__ __align__(16) uint64_t sk[N_];   // 16 KB
    __shared__ int pcnt[4 * 64];
    const int tid = threadIdx.x;

    if (blockIdx.x >= RANK_BLOCKS) {
        if (blockIdx.x == RANK_BLOCKS && tid == 0) *gcnt = 0;  // before knn (stream order)
        // weff/btot: 4 lanes per output, 32 MACs each, shfl-reduce.
        const int g = (blockIdx.x - RANK_BLOCKS) * 256 + tid;
        const int o = g >> 2, q = g & 3;
        float acc = 0.f;
        if (o < H_ * KK * 2) {
            const int e = o / 20, r = o % 20, k = r >> 1, c = r & 1;
            const float* w2p = W2 + e * H_ + q * 32;
            const float* wcp = Wconv + (q * 32) * (2 * KK) + c * KK + k;
#pragma unroll 8
            for (int h = 0; h < 32; ++h)
                acc += w2p[h] * wcp[h * (2 * KK)];
        } else {
            const int e = o - H_ * KK * 2;
            const float* w2p = W2 + e * H_ + q * 32;
            const float* bcp = bconv + q * 32;
#pragma unroll 8
            for (int h = 0; h < 32; ++h) acc += w2p[h] * bcp[h];
        }
        acc += __shfl_xor(acc, 1, 64);
        acc += __shfl_xor(acc, 2, 64);
        if (q == 0) {
            if (o < H_ * KK * 2) weff[o] = acc;
            else {
                const int e = o - H_ * KK * 2;
                btot[e] = acc + b1[e] + b2[e];
            }
        }
        return;
    }

    const int b  = blockIdx.x >> 5;   // 32 seg-blocks per batch
    const int sg = blockIdx.x & 31;   // 64-element segment
    const float2* xb = (const float2*)(x + (size_t)b * N_ * 2);

    for (int i = tid; i < N_; i += 256)
        sk[i] = ((uint64_t)f32_ordered(xb[i].x) << 32) | (uint32_t)i;
    __syncthreads();

    const int el = tid & 63;
    const int pt = tid >> 6;
    const uint64_t kown = sk[sg * 64 + el];
    const ulonglong2* sk2 = (const ulonglong2*)sk + pt * 256;
    int cnt = 0;
#pragma unroll 2
    for (int j = 0; j < 256; j += 4) {
        ulonglong2 t0 = sk2[j + 0];
        ulonglong2 t1 = sk2[j + 1];
        ulonglong2 t2 = sk2[j + 2];
        ulonglong2 t3 = sk2[j + 3];
        cnt += (int)(t0.x < kown) + (int)(t0.y < kown)
             + (int)(t1.x < kown) + (int)(t1.y < kown)
             + (int)(t2.x < kown) + (int)(t2.y < kown)
             + (int)(t3.x < kown) + (int)(t3.y < kown);
    }
    pcnt[pt * 64 + el] = cnt;
    __syncthreads();

    if (tid < 64) {
        const int r = pcnt[tid] + pcnt[64 + tid] + pcnt[128 + tid] + pcnt[192 + tid];
        const int i = sg * 64 + tid;
        float2 p = xb[i];
        float sm = p.x * p.x + p.y * p.y;   // no FMA (np sum convention)
        xsorted[(size_t)b * N_ + r] =
            make_float4(p.x, p.y, sm, __uint_as_float((uint32_t)i));
    }
}

// ---- main kernel v5: 512 blocks x 512 threads (R3 residency: 2 blocks/CU,
// 16 waves/CU) pulling HALF-TILE items (32 queries = 1 chunk) from a global
// atomic queue (1024 items -> ~2/block; fast blocks steal more). Items are
// ordered center-first so dense (long) tiles start earliest. Wave w owns
// chunks == w (mod 8); lanes: q = l&31 (query), hh = l>>5 (even/odd chunk
// positions) -> 16 lists/query, merge-16. Per-candidate math, merge
// selection, and epilogue order identical to R4 -> identical output.
__global__ __launch_bounds__(512, 4) void knn_conv_kernel(
    const float4* __restrict__ xsorted,
    const float* __restrict__ W1,
    const float* __restrict__ weff,
    const float* __restrict__ btot,
    int* __restrict__ gcnt,
    float* __restrict__ out)
{
#pragma clang fp contract(off)
    __shared__ float4   xs4[N_];           // 32 KB
    __shared__ uint64_t mkeys[32 * 161];   // 41.2 KB (16 lists x 10, stride 161)
    __shared__ float    wcoord[32 * 21];   //  2.6 KB
    __shared__ float    hbound[32 * 17];   //  2.1 KB
    __shared__ int      s_item;

    const int tid = threadIdx.x;
    const int w   = tid >> 6;        // wave 0..7
    const int l   = tid & 63;
    const int q   = l & 31;          // query within half-tile
    const int hh  = l >> 5;          // 0: even chunk positions, 1: odd

    // hoist epilogue weights once (uniform across items)
    const int e = tid & 127;
    float we[20];
    {
        const float4* wp = (const float4*)(weff + e * 20);
#pragma unroll
        for (int r = 0; r < 5; ++r) {
            float4 v = wp[r];
            we[4 * r + 0] = v.x; we[4 * r + 1] = v.y;
            we[4 * r + 2] = v.z; we[4 * r + 3] = v.w;
        }
    }
    const float w1x = W1[e * 2 + 0];
    const float w1y = W1[e * 2 + 1];
    const float bt  = btot[e];

    int cur_b = -1;
    for (;;) {
        __syncthreads();                       // protect s_item + xs4 + mkeys
        if (tid == 0) s_item = atomicAdd(gcnt, 1);
        __syncthreads();
        const int item = s_item;
        if (item >= NITEMS) break;
        const int b = item >> 6;
        const int u = item & 63;               // center-first chunk order
        const int ht = (u & 1) ? (32 - ((u + 1) >> 1)) : (32 + (u >> 1));

        if (b != cur_b) {                      // uniform branch
            const float4* xb = xsorted + (size_t)b * N_;
            for (int i = tid; i < N_; i += 512) xs4[i] = xb[i];
            cur_b = b;
            __syncthreads();
        }

        const float4 qv = xs4[ht * 32 + q];
        const float  qx = qv.x, qy = qv.y, sqn = qv.z;
        const float  qa  = xs4[ht * 32].x;      // half-tile x-range (uniform)
        const float  qbx = xs4[ht * 32 + 31].x;

        const uint64_t KINIT = (((uint64_t)0x7F7FFFFFu) << 32) | 0x3FFFFFu;
        uint64_t hk[KK];
#pragma unroll
        for (int j = 0; j < KK; ++j) hk[j] = KINIT;
        float h9d  = FLT_MAX;
        float shb  = FLT_MAX;
        float gate = FLT_MAX;

        auto insert = [&](float dc, float cw, int m) {
            uint32_t oi = __float_as_uint(cw);
            uint64_t key = ((uint64_t)__float_as_uint(dc) << 32)
                         | (oi << 11) | (uint32_t)m;
            if (key < hk[KK - 1]) {
#pragma unroll
                for (int j = KK - 1; j >= 1; --j) {
                    bool cj  = key < hk[j];
                    bool cjm = key < hk[j - 1];
                    hk[j] = cj ? (cjm ? hk[j - 1] : key) : hk[j];
                }
                hk[0] = (key < hk[0]) ? key : hk[0];
            }
            h9d  = __uint_as_float((uint32_t)(hk[KK - 1] >> 32));
            gate = fminf(h9d, shb);
        };

        // half hh scans positions mc+hh, mc+hh+2, ... (16 of 32, ILP-4)
        auto scan_chunk = [&](int mc) {
            const int base = mc + hh;
#pragma unroll
            for (int jj = 0; jj < 4; ++jj) {
                const int m0 = base + jj * 8;
                float4 c0 = xs4[m0 + 0];
                float4 c1 = xs4[m0 + 2];
                float4 c2 = xs4[m0 + 4];
                float4 c3 = xs4[m0 + 6];
                float dc0, dc1, dc2, dc3;
                { float s = sqn + c0.z; float pr = qx * c0.x;
                  float dt = __builtin_fmaf(qy, c0.y, pr);
                  float d2 = __builtin_fmaf(-2.0f, dt, s); dc0 = d2 > 0.0f ? d2 : 0.0f; }
                { float s = sqn + c1.z; float pr = qx * c1.x;
                  float dt = __builtin_fmaf(qy, c1.y, pr);
                  float d2 = __builtin_fmaf(-2.0f, dt, s); dc1 = d2 > 0.0f ? d2 : 0.0f; }
                { float s = sqn + c2.z; float pr = qx * c2.x;
                  float dt = __builtin_fmaf(qy, c2.y, pr);
                  float d2 = __builtin_fmaf(-2.0f, dt, s); dc2 = d2 > 0.0f ? d2 : 0.0f; }
                { float s = sqn + c3.z; float pr = qx * c3.x;
                  float dt = __builtin_fmaf(qy, c3.y, pr);
                  float d2 = __builtin_fmaf(-2.0f, dt, s); dc3 = d2 > 0.0f ? d2 : 0.0f; }
                if (dc0 <= gate) insert(dc0, c0.w, m0 + 0);
                if (dc1 <= gate) insert(dc1, c1.w, m0 + 2);
                if (dc2 <= gate) insert(dc2, c2.w, m0 + 4);
                if (dc3 <= gate) insert(dc3, c3.w, m0 + 6);
            }
        };

        // phase 1: nearest owned chunk (mod 8)
        const int a8  = (w - ht) & 7;
        const int c1_ = ht + a8;
        const int c2_ = c1_ - 8;
        int c_near = (a8 <= 4) ? c1_ : c2_;
        if (c1_ > NCH - 1) c_near = c2_;
        if (c2_ < 0)       c_near = c1_;
        scan_chunk(c_near * SUB);

        // cross-list bound exchange: min over 16 partial 10th-bests (each
        // list holds 10 of 16 real candidates) is a valid upper bound on the
        // true 10th-best -> safe block-wide gate.
        hbound[q * 17 + (w * 2 + hh)] = h9d;
        __syncthreads();
        {
            const float* hb = &hbound[q * 17];
            float m0 = fminf(hb[0],  hb[1]);
            float m1 = fminf(hb[2],  hb[3]);
            float m2 = fminf(hb[4],  hb[5]);
            float m3 = fminf(hb[6],  hb[7]);
            float m4 = fminf(hb[8],  hb[9]);
            float m5 = fminf(hb[10], hb[11]);
            float m6 = fminf(hb[12], hb[13]);
            float m7 = fminf(hb[14], hb[15]);
            shb = fminf(fminf(fminf(m0, m1), fminf(m2, m3)),
                        fminf(fminf(m4, m5), fminf(m6, m7)));
            gate = fminf(h9d, shb);
        }

        // phase 2: two-pointer outward expansion (step 8); wave-uniform.
        int  cl = c_near - 8, cr = c_near + 8;
        bool la = (cl >= 0), ra = (cr <= NCH - 1);
        while (la || ra) {
            float wm = gate;
            wm = fmaxf(wm, __shfl_xor(wm, 1,  64));
            wm = fmaxf(wm, __shfl_xor(wm, 2,  64));
            wm = fmaxf(wm, __shfl_xor(wm, 4,  64));
            wm = fmaxf(wm, __shfl_xor(wm, 8,  64));
            wm = fmaxf(wm, __shfl_xor(wm, 16, 64));
            wm = fmaxf(wm, __shfl_xor(wm, 32, 64));
            float gl = la ? (qa - xs4[cl * SUB + SUB - 1].x) : FLT_MAX;  // >= 0
            float gr = ra ? (xs4[cr * SUB].x - qbx)          : FLT_MAX;  // >= 0
            bool pickL = la && (!ra || gl <= gr);
            if (pickL) {
                if (__builtin_fmaf(gl, gl, -4e-6f) > wm) la = false;
                else { scan_chunk(cl * SUB); cl -= 8; la = (cl >= 0); }
            } else {
                if (__builtin_fmaf(gr, gr, -4e-6f) > wm) ra = false;
                else { scan_chunk(cr * SUB); cr += 8; ra = (cr <= NCH - 1); }
            }
        }

        // publish partial lists: list li = w*2+hh of query q
        {
            const int mb = q * 161 + (w * 2 + hh) * 10;
#pragma unroll
            for (int j = 0; j < KK; ++j) mkeys[mb + j] = hk[j];
        }
        __syncthreads();

        // parallel merge: 16 lanes per query (qm = tid>>4, r = tid&15);
        // keys unique -> exactly one winner per selection.
        {
            const int qm = tid >> 4;
            const int r  = tid & 15;
            const int mb = qm * 161 + r * 10;
            int p = 0;
#pragma unroll
            for (int sel = 0; sel < KK; ++sel) {
                uint64_t v = (p < KK) ? mkeys[mb + p] : 0xFFFFFFFFFFFFFFFFull;
                uint64_t t1 = __shfl_xor((unsigned long long)v, 1, 64);
                uint64_t m1 = v  < t1 ? v  : t1;
                uint64_t t2 = __shfl_xor((unsigned long long)m1, 2, 64);
                uint64_t m2 = m1 < t2 ? m1 : t2;
                uint64_t t4 = __shfl_xor((unsigned long long)m2, 4, 64);
                uint64_t m4 = m2 < t4 ? m2 : t4;
                uint64_t t8 = __shfl_xor((unsigned long long)m4, 8, 64);
                uint64_t vm = m4 < t8 ? m4 : t8;
                if (v == vm) {
                    ++p;
                    float4 c = xs4[(int)(vm & 0x7FF)];
                    const int k = (KK - 1) - sel;      // flip: nearest -> k=9
                    wcoord[qm * 21 + 2 * k + 0] = c.x;
                    wcoord[qm * 21 + 2 * k + 1] = c.y;
                }
            }
        }
        __syncthreads();

        // epilogue: thread -> channel e; 32 queries x 128 channels.
        const int qb_ = tid >> 7;                  // 0..3
        const size_t obase = (size_t)b * N_ * H_;
#pragma unroll
        for (int jj = 0; jj < 8; ++jj) {
            const int qq = qb_ + 4 * jj;
            float4 xq = xs4[ht * 32 + qq];
            uint32_t orig = __float_as_uint(xq.w);
            const float* wc = &wcoord[qq * 21];
            float acc = bt;
            acc += xq.x * w1x;
            acc += xq.y * w1y;
#pragma unroll
            for (int k = 0; k < KK; ++k) {
                acc += wc[2 * k + 0] * we[2 * k + 0];
                acc += wc[2 * k + 1] * we[2 * k + 1];
            }
            out[obase + (size_t)orig * H_ + e] = acc;
        }
    }
}

extern "C" void kernel_launch(void* const* d_in, const int* in_sizes, int n_in,
                              void* d_out, int out_size, void* d_ws, size_t ws_size,
                              hipStream_t stream) {
    const float* x     = (const float*)d_in[0];
    const float* Wconv = (const float*)d_in[1];
    const float* bconv = (const float*)d_in[2];
    const float* W1    = (const float*)d_in[3];
    const float* b1    = (const float*)d_in[4];
    const float* W2    = (const float*)d_in[5];
    const float* b2    = (const float*)d_in[6];
    float* out  = (float*)d_out;
    float* weff = (float*)d_ws;                           // 2560 floats
    float* btot = weff + H_ * KK * 2;                     // 128 floats
    int*   gcnt = (int*)((char*)d_ws + 12288);            // in padding below 16384
    float4* xsorted = (float4*)((char*)d_ws + 16384);     // 16*2048*16B

    setup_kernel<<<dim3(RANK_BLOCKS + WEFF_BLOCKS), dim3(256), 0, stream>>>(
        x, Wconv, bconv, b1, W2, b2, xsorted, weff, btot, gcnt);
    knn_conv_kernel<<<dim3(512), dim3(512), 0, stream>>>(
        xsorted, W1, weff, btot, gcnt, out);
}

// Round 6
// 150.854 us; speedup vs baseline: 1.1504x; 1.1504x over previous
//
#include <hip/hip_runtime.h>
#include <cfloat>
#include <stdint.h>

#define B_   16
#define N_   2048
#define KK   10          // window = K+1
#define H_   128
#define SUB  32          // chunk size
#define NCH  (N_ / SUB)  // 64 chunks

#define RANK_BLOCKS (B_ * 32)                  // 512: 64-elem segments, 256 thr
#define WEFF_OUT    (H_ * KK * 2 + H_)         // 2688 outputs
#define WEFF_BLOCKS ((WEFF_OUT * 4) / 256)     // 42 (4 lanes/output, exact)

__device__ inline uint32_t f32_ordered(float f) {
    uint32_t u = __float_as_uint(f);
    return (u & 0x80000000u) ? ~u : (u | 0x80000000u);
}

// ---- setup (R3 structure, ~6us): rank-by-count sort; unique keys ->
// exact permutation, output bitwise-identical to the original bitonic.
__global__ __launch_bounds__(256) void setup_kernel(
    const float* __restrict__ x,
    const float* __restrict__ Wconv, const float* __restrict__ bconv,
    const float* __restrict__ b1,    const float* __restrict__ W2,
    const float* __restrict__ b2,
    float4* __restrict__ xsorted,    // [B][N] (px,py,sm,orig_idx_bits)
    float*  __restrict__ weff,       // [H*20]
    float*  __restrict__ btot)       // [H]
{
#pragma clang fp contract(off)
    __shared__ __align__(16) uint64_t sk[N_];   // 16 KB
    __shared__ int pcnt[4 * 64];
    const int tid = threadIdx.x;

    if (blockIdx.x >= RANK_BLOCKS) {
        // weff/btot: 4 lanes per output, 32 MACs each, shfl-reduce.
        const int g = (blockIdx.x - RANK_BLOCKS) * 256 + tid;
        const int o = g >> 2, q = g & 3;
        float acc = 0.f;
        if (o < H_ * KK * 2) {
            const int e = o / 20, r = o % 20, k = r >> 1, c = r & 1;
            const float* w2p = W2 + e * H_ + q * 32;
            const float* wcp = Wconv + (q * 32) * (2 * KK) + c * KK + k;
#pragma unroll 8
            for (int h = 0; h < 32; ++h)
                acc += w2p[h] * wcp[h * (2 * KK)];
        } else {
            const int e = o - H_ * KK * 2;
            const float* w2p = W2 + e * H_ + q * 32;
            const float* bcp = bconv + q * 32;
#pragma unroll 8
            for (int h = 0; h < 32; ++h) acc += w2p[h] * bcp[h];
        }
        acc += __shfl_xor(acc, 1, 64);
        acc += __shfl_xor(acc, 2, 64);
        if (q == 0) {
            if (o < H_ * KK * 2) weff[o] = acc;
            else {
                const int e = o - H_ * KK * 2;
                btot[e] = acc + b1[e] + b2[e];
            }
        }
        return;
    }

    const int b  = blockIdx.x >> 5;   // 32 seg-blocks per batch
    const int sg = blockIdx.x & 31;   // 64-element segment
    const float2* xb = (const float2*)(x + (size_t)b * N_ * 2);

    for (int i = tid; i < N_; i += 256)
        sk[i] = ((uint64_t)f32_ordered(xb[i].x) << 32) | (uint32_t)i;
    __syncthreads();

    const int el = tid & 63;
    const int pt = tid >> 6;
    const uint64_t kown = sk[sg * 64 + el];
    const ulonglong2* sk2 = (const ulonglong2*)sk + pt * 256;
    int cnt = 0;
#pragma unroll 2
    for (int j = 0; j < 256; j += 4) {
        ulonglong2 t0 = sk2[j + 0];
        ulonglong2 t1 = sk2[j + 1];
        ulonglong2 t2 = sk2[j + 2];
        ulonglong2 t3 = sk2[j + 3];
        cnt += (int)(t0.x < kown) + (int)(t0.y < kown)
             + (int)(t1.x < kown) + (int)(t1.y < kown)
             + (int)(t2.x < kown) + (int)(t2.y < kown)
             + (int)(t3.x < kown) + (int)(t3.y < kown);
    }
    pcnt[pt * 64 + el] = cnt;
    __syncthreads();

    if (tid < 64) {
        const int r = pcnt[tid] + pcnt[64 + tid] + pcnt[128 + tid] + pcnt[192 + tid];
        const int i = sg * 64 + tid;
        float2 p = xb[i];
        float sm = p.x * p.x + p.y * p.y;   // no FMA (np sum convention)
        xsorted[(size_t)b * N_ + r] =
            make_float4(p.x, p.y, sm, __uint_as_float((uint32_t)i));
    }
}

// ---- main kernel v6: QUERY-partitioned waves. 512 threads = 8 waves per
// 64-query tile; wave w owns the 8 CONSECUTIVE queries [w*8, w*8+8).
// Lane l: query qm = tid>>3, sub-lane r = tid&7 handling chunk positions
// r, r+8, r+16, r+24 (4 candidates/chunk/lane; union of 8 sub-lanes = full
// chunk). vs R3's chunk-partitioned waves: d2 work/lane ~13x lower, the
// divergent 60-VALU insert ladder fires ~8x less, the 8-query window makes
// gap-termination ~8x tighter, and partial lists stay in REGISTERS in
// exactly the lanes merge-8 wants -> mkeys LDS + 2 barriers eliminated.
// Candidate set, tie-break keys and FP order unchanged -> identical output.
__global__ __launch_bounds__(512, 4) void knn_conv_kernel(
    const float4* __restrict__ xsorted,
    const float* __restrict__ W1,
    const float* __restrict__ weff,
    const float* __restrict__ btot,
    float* __restrict__ out)
{
#pragma clang fp contract(off)
    __shared__ float4 xs4[N_];           // 32 KB
    __shared__ float  wcoord[64 * 21];   //  5.25 KB

    const int tid  = threadIdx.x;
    const int w    = tid >> 6;        // wave 0..7
    const int r    = tid & 7;         // sub-lane: candidate slice
    const int qm   = tid >> 3;        // query within tile (0..63)
    const int b    = blockIdx.x >> 5;
    const int tile = blockIdx.x & 31;

    const float4* xb = xsorted + (size_t)b * N_;
    for (int i = tid; i < N_; i += 512) xs4[i] = xb[i];
    __syncthreads();

    const float4 qv = xs4[tile * 64 + qm];
    const float  qx = qv.x, qy = qv.y, sqn = qv.z;
    const int    gfirst = tile * 64 + w * 8;      // wave's query group
    const float  qa  = xs4[gfirst].x;             // group x-range (uniform)
    const float  qbx = xs4[gfirst + 7].x;

    // sorted-10 of u64 keys: (d2_bits<<32)|(orig_idx<<11)|sorted_pos.
    const uint64_t KINIT = (((uint64_t)0x7F7FFFFFu) << 32) | 0x3FFFFFu;
    uint64_t hk[KK];
#pragma unroll
    for (int j = 0; j < KK; ++j) hk[j] = KINIT;
    float h9d  = FLT_MAX;   // 10th-best of own candidate subset
    float shb  = FLT_MAX;   // query-group shared bound (min over 8 sub-lanes)
    float gate = FLT_MAX;   // fminf(h9d, shb)

    auto insert = [&](float dc, float cw, int m) {
        uint32_t oi = __float_as_uint(cw);
        uint64_t key = ((uint64_t)__float_as_uint(dc) << 32)
                     | (oi << 11) | (uint32_t)m;
        if (key < hk[KK - 1]) {
#pragma unroll
            for (int j = KK - 1; j >= 1; --j) {
                bool cj  = key < hk[j];
                bool cjm = key < hk[j - 1];
                hk[j] = cj ? (cjm ? hk[j - 1] : key) : hk[j];
            }
            hk[0] = (key < hk[0]) ? key : hk[0];
        }
        h9d  = __uint_as_float((uint32_t)(hk[KK - 1] >> 32));
        gate = fminf(h9d, shb);
    };

    // sub-lane r scans positions mc+r, +8, +16, +24 (per-lane addresses;
    // 8 distinct float4 lines x 8-way broadcast = conflict-free).
    auto scan_chunk = [&](int mc) {
        const int m0 = mc + r;
        float4 c0 = xs4[m0 + 0];
        float4 c1 = xs4[m0 + 8];
        float4 c2 = xs4[m0 + 16];
        float4 c3 = xs4[m0 + 24];
        float dc0, dc1, dc2, dc3;
        { float s = sqn + c0.z; float pr = qx * c0.x;
          float dt = __builtin_fmaf(qy, c0.y, pr);
          float d2 = __builtin_fmaf(-2.0f, dt, s); dc0 = d2 > 0.0f ? d2 : 0.0f; }
        { float s = sqn + c1.z; float pr = qx * c1.x;
          float dt = __builtin_fmaf(qy, c1.y, pr);
          float d2 = __builtin_fmaf(-2.0f, dt, s); dc1 = d2 > 0.0f ? d2 : 0.0f; }
        { float s = sqn + c2.z; float pr = qx * c2.x;
          float dt = __builtin_fmaf(qy, c2.y, pr);
          float d2 = __builtin_fmaf(-2.0f, dt, s); dc2 = d2 > 0.0f ? d2 : 0.0f; }
        { float s = sqn + c3.z; float pr = qx * c3.x;
          float dt = __builtin_fmaf(qy, c3.y, pr);
          float d2 = __builtin_fmaf(-2.0f, dt, s); dc3 = d2 > 0.0f ? d2 : 0.0f; }
        if (dc0 <= gate) insert(dc0, c0.w, m0 + 0);
        if (dc1 <= gate) insert(dc1, c1.w, m0 + 8);
        if (dc2 <= gate) insert(dc2, c2.w, m0 + 16);
        if (dc3 <= gate) insert(dc3, c3.w, m0 + 24);
    };

    // group-min (gate/shb) + wave-max (termination) in one 6-shfl pass.
    // Each sub-lane's 10th-best is an upper bound on the query's true
    // 10th-best; min over the 8 sub-lanes is too -> safe accept/skip gate.
    auto bounds = [&]() {
        float gb = h9d;
        gb = fminf(gb, __shfl_xor(gb, 1, 64));
        gb = fminf(gb, __shfl_xor(gb, 2, 64));
        gb = fminf(gb, __shfl_xor(gb, 4, 64));
        shb = gb; gate = fminf(h9d, gb);
        float wm = gb;
        wm = fmaxf(wm, __shfl_xor(wm, 8,  64));
        wm = fmaxf(wm, __shfl_xor(wm, 16, 64));
        wm = fmaxf(wm, __shfl_xor(wm, 32, 64));
        return wm;   // max over the wave's 8 queries of their bounds
    };

    // phase 1: home chunk trio (12 candidates/lane >= 10 -> lists full).
    // All 8 queries of the wave lie in chunk home = tile*2 + (w>>2).
    const int home = tile * 2 + (w >> 2);
    int c0s = home - 1;
    if (c0s < 0) c0s = 0;
    if (c0s > NCH - 3) c0s = NCH - 3;
    scan_chunk((c0s + 0) * SUB);
    scan_chunk((c0s + 1) * SUB);
    scan_chunk((c0s + 2) * SUB);

    // phase 2: two-pointer outward, step 1, both sides per bounds() refresh
    // (stale-wm on the right is conservative: wm only shrinks). Gaps are
    // monotone per side -> a failed skip test kills that side for good.
    int  cl = c0s - 1, cr = c0s + 3;
    bool la = (cl >= 0), ra = (cr <= NCH - 1);
    while (la || ra) {
        float wm = bounds();
        if (la) {
            float gl = qa - xs4[cl * SUB + SUB - 1].x;            // >= 0
            if (__builtin_fmaf(gl, gl, -4e-6f) > wm) la = false;  // margin >> f32 d2 err
            else { scan_chunk(cl * SUB); cl -= 1; la = (cl >= 0); }
        }
        if (ra) {
            float gr = xs4[cr * SUB].x - qbx;                     // >= 0
            if (__builtin_fmaf(gr, gr, -4e-6f) > wm) ra = false;
            else { scan_chunk(cr * SUB); cr += 1; ra = (cr <= NCH - 1); }
        }
    }

    // hoist epilogue weights (latency overlaps merge + barrier)
    const int e = tid & 127;
    float we[20];
    {
        const float4* wp = (const float4*)(weff + e * 20);
#pragma unroll
        for (int rr = 0; rr < 5; ++rr) {
            float4 v = wp[rr];
            we[4 * rr + 0] = v.x; we[4 * rr + 1] = v.y;
            we[4 * rr + 2] = v.z; we[4 * rr + 3] = v.w;
        }
    }
    const float w1x = W1[e * 2 + 0];
    const float w1y = W1[e * 2 + 1];
    const float bt  = btot[e];

    // register merge: 8 sub-lane lists per query are already resident in
    // lanes (qm, r) -- exactly merge-8's layout. Head = hk[0]; winner
    // shift-registers its list (static indexing -> stays in VGPRs).
    // Keys unique -> exactly one winner per selection; 80 real keys >= 10.
    {
#pragma unroll
        for (int sel = 0; sel < KK; ++sel) {
            uint64_t v  = hk[0];
            uint64_t t1 = __shfl_xor((unsigned long long)v, 1, 64);
            uint64_t m1 = v  < t1 ? v  : t1;
            uint64_t t2 = __shfl_xor((unsigned long long)m1, 2, 64);
            uint64_t m2 = m1 < t2 ? m1 : t2;
            uint64_t t4 = __shfl_xor((unsigned long long)m2, 4, 64);
            uint64_t vm = m2 < t4 ? m2 : t4;
            if (v == vm) {
#pragma unroll
                for (int j = 0; j < KK - 1; ++j) hk[j] = hk[j + 1];
                hk[KK - 1] = 0xFFFFFFFFFFFFFFFFull;
                float4 c = xs4[(int)(vm & 0x7FF)];
                const int k = (KK - 1) - sel;          // flip: nearest -> k=9
                wcoord[qm * 21 + 2 * k + 0] = c.x;
                wcoord[qm * 21 + 2 * k + 1] = c.y;
            }
        }
    }
    __syncthreads();

    // epilogue: thread -> channel e; rows scattered to ORIGINAL indices
    // (128 consecutive floats per row, coalesced per wave-store).
    const int qb_ = tid >> 7;
    const size_t obase = (size_t)b * N_ * H_;
#pragma unroll
    for (int jj = 0; jj < 16; ++jj) {
        const int qq = qb_ + 4 * jj;
        float4 xq = xs4[tile * 64 + qq];
        uint32_t orig = __float_as_uint(xq.w);
        const float* wc = &wcoord[qq * 21];
        float acc = bt;
        acc += xq.x * w1x;
        acc += xq.y * w1y;
#pragma unroll
        for (int k = 0; k < KK; ++k) {
            acc += wc[2 * k + 0] * we[2 * k + 0];
            acc += wc[2 * k + 1] * we[2 * k + 1];
        }
        out[obase + (size_t)orig * H_ + e] = acc;
    }
}

extern "C" void kernel_launch(void* const* d_in, const int* in_sizes, int n_in,
                              void* d_out, int out_size, void* d_ws, size_t ws_size,
                              hipStream_t stream) {
    const float* x     = (const float*)d_in[0];
    const float* Wconv = (const float*)d_in[1];
    const float* bconv = (const float*)d_in[2];
    const float* W1    = (const float*)d_in[3];
    const float* b1    = (const float*)d_in[4];
    const float* W2    = (const float*)d_in[5];
    const float* b2    = (const float*)d_in[6];
    float* out  = (float*)d_out;
    float* weff = (float*)d_ws;                           // 2560 floats
    float* btot = weff + H_ * KK * 2;                     // 128 floats
    float4* xsorted = (float4*)((char*)d_ws + 16384);     // 16*2048*16B

    setup_kernel<<<dim3(RANK_BLOCKS + WEFF_BLOCKS), dim3(256), 0, stream>>>(
        x, Wconv, bconv, b1, W2, b2, xsorted, weff, btot);
    knn_conv_kernel<<<dim3(B_ * (N_ / 64)), dim3(512), 0, stream>>>(
        xsorted, W1, weff, btot, out);
}